// Round 2
// baseline (427.860 us; speedup 1.0000x reference)
//
#include <hip/hip_runtime.h>
#include <cstdint>
#include <cstddef>

// VQ-VAE quantization forward, MI355X/gfx950.
// Outputs (concat in d_out, fp32): quantized (64*400*1024), commitment_loss (1), perplexity (1).

namespace {
constexpr int kNT = 25600;           // N*T rows
constexpr int kD  = 1024;            // feature dim
constexpr int kM  = 256;             // codebook size
constexpr int kBM = 64;              // rows per block
constexpr int kBK = 16;              // k-tile
constexpr int kKT = kD / kBK;        // 64 k-tiles
constexpr size_t kQElems = (size_t)kNT * kD;   // 26214400

// workspace layout (float offsets)
constexpr int WS_EMBT = 0;                 // embT[k][m]: 1024x256 normalized, transposed
constexpr int WS_E2N  = kD * kM;           // ||e_norm||^2 per code (256)
constexpr int WS_SCL  = WS_E2N + kM;       // ||e_raw|| + 1e-4 per code (256)
constexpr int WS_E2R  = WS_SCL + kM;       // ||e_raw||^2 per code (256)
constexpr int WS_COM  = WS_E2R + kM;       // commitment sum accumulator (1, +3 pad)
constexpr int WS_HIST = WS_COM + 4;        // histogram, 256 ints
constexpr int WS_ZERO_BYTES = (WS_HIST + kM - WS_COM) * 4;
}

typedef __attribute__((address_space(3))) unsigned int        lds_u32;
typedef const __attribute__((address_space(1))) unsigned int  glb_u32;

__device__ __forceinline__ void gl2lds16(const float* g, float* l) {
  // 16B per lane, LDS dest = wave-uniform base + lane*16
  __builtin_amdgcn_global_load_lds((glb_u32*)g, (lds_u32*)l, 16, 0, 0);
}

// ---------------- kernel 1: normalize codebook, transpose, per-code stats ----------------
__global__ __launch_bounds__(256) void vq_normalize(const float* __restrict__ emb,
                                                    float* __restrict__ ws) {
  const int m = blockIdx.x;
  const int t = threadIdx.x;
  float* embT = ws + WS_EMBT;
  const float4 v = reinterpret_cast<const float4*>(emb + (size_t)m * kD)[t];
  float s = v.x * v.x + v.y * v.y + v.z * v.z + v.w * v.w;
#pragma unroll
  for (int mask = 32; mask >= 1; mask >>= 1) s += __shfl_xor(s, mask);
  __shared__ float red[4];
  if ((t & 63) == 0) red[t >> 6] = s;
  __syncthreads();
  const float tot = red[0] + red[1] + red[2] + red[3];
  const float sc  = sqrtf(tot) + 1e-4f;
  const float inv = 1.0f / sc;
  const float4 nv = make_float4(v.x * inv, v.y * inv, v.z * inv, v.w * inv);
  embT[(4 * t + 0) * kM + m] = nv.x;
  embT[(4 * t + 1) * kM + m] = nv.y;
  embT[(4 * t + 2) * kM + m] = nv.z;
  embT[(4 * t + 3) * kM + m] = nv.w;
  float s2 = nv.x * nv.x + nv.y * nv.y + nv.z * nv.z + nv.w * nv.w;
#pragma unroll
  for (int mask = 32; mask >= 1; mask >>= 1) s2 += __shfl_xor(s2, mask);
  __syncthreads();                 // everyone done reading red
  if ((t & 63) == 0) red[t >> 6] = s2;
  __syncthreads();
  if (t == 0) {
    ws[WS_E2N + m] = red[0] + red[1] + red[2] + red[3];
    ws[WS_SCL + m] = sc;
    ws[WS_E2R + m] = tot;
  }
}

// ---------------- kernel 2: distances GEMM + argmin + gather + stats ----------------
__global__ __launch_bounds__(256) void vq_main(const float* __restrict__ x,
                                               const float* __restrict__ emb,
                                               const float* __restrict__ ws_c,
                                               float* __restrict__ out,
                                               float* __restrict__ commit_sum,
                                               int* __restrict__ hist) {
  __shared__ float Xs[kBM][kBK];    // [row][k] — lane-contiguous for global_load_lds
  __shared__ float Es[kBK][kM];     // [k][col] — lane-contiguous for global_load_lds
  __shared__ float e2n_s[kM], scl_s[kM], e2r_s[kM];
  __shared__ int   idx_s[kBM];

  const int t    = threadIdx.x;
  const int tx   = t & 31;
  const int ty   = t >> 5;
  const int wave = t >> 6;
  const int lane = t & 63;
  const int r0   = blockIdx.x * kBM;

  e2n_s[t] = ws_c[WS_E2N + t];
  scl_s[t] = ws_c[WS_SCL + t];
  e2r_s[t] = ws_c[WS_E2R + t];

  const float* embT = ws_c + WS_EMBT;
  // X staging: thread t -> row t/4, k-quad t%4 (flat LDS offset == 16B*lane); 256*16B = full 4KB tile
  const float* xg = x + (size_t)(r0 + (t >> 2)) * kD + (t & 3) * 4;
  // E staging: tile is 16 rows x 256 floats = 16KB; one wave-load covers 1KB (one k-row).
  // Wave w issues 4 loads for k-rows 4w..4w+3 (global rows contiguous in embT).
  const float* eg = embT + (size_t)(4 * wave) * kM + 4 * lane;
  float* xlds = &Xs[wave * 16][0];
  float* elds = &Es[4 * wave][0];

  float acc[8][8] = {};
  float x2a[8] = {0.f, 0.f, 0.f, 0.f, 0.f, 0.f, 0.f, 0.f};

#pragma unroll 1
  for (int kt = 0; kt < kKT; ++kt) {
    gl2lds16(xg + kt * kBK, xlds);
#pragma unroll
    for (int r = 0; r < 4; ++r) {
      gl2lds16(eg + (size_t)kt * kBK * kM + r * kM, elds + r * kM);
    }
    __syncthreads();   // drains vmcnt(0): tiles ready
#pragma unroll
    for (int k4 = 0; k4 < 4; ++k4) {
      float4 xr[8];
#pragma unroll
      for (int rr = 0; rr < 8; ++rr) {
        const int r = (rr < 4) ? (4 * ty + rr) : (32 + 4 * ty + (rr - 4));
        xr[rr] = *reinterpret_cast<const float4*>(&Xs[r][4 * k4]);
        x2a[rr] += xr[rr].x * xr[rr].x + xr[rr].y * xr[rr].y +
                   xr[rr].z * xr[rr].z + xr[rr].w * xr[rr].w;
      }
#pragma unroll
      for (int kk = 0; kk < 4; ++kk) {
        const float4 ea = *reinterpret_cast<const float4*>(&Es[4 * k4 + kk][4 * tx]);
        const float4 eb = *reinterpret_cast<const float4*>(&Es[4 * k4 + kk][128 + 4 * tx]);
#pragma unroll
        for (int rr = 0; rr < 8; ++rr) {
          const float xv = (&xr[rr].x)[kk];
          acc[rr][0] += xv * ea.x;  acc[rr][1] += xv * ea.y;
          acc[rr][2] += xv * ea.z;  acc[rr][3] += xv * ea.w;
          acc[rr][4] += xv * eb.x;  acc[rr][5] += xv * eb.y;
          acc[rr][6] += xv * eb.z;  acc[rr][7] += xv * eb.w;
        }
      }
    }
    __syncthreads();   // protect LDS before next tile's async loads
  }

  // ---- argmin over 256 codes per row (comparator drops row-constant ||x||^2) ----
  float e2nj[8]; int jc[8];
#pragma unroll
  for (int jj = 0; jj < 8; ++jj) {
    jc[jj]   = (jj < 4) ? (4 * tx + jj) : (128 + 4 * tx + (jj - 4));
    e2nj[jj] = e2n_s[jc[jj]];
  }
  float commit_loc = 0.0f;
  const bool writer = (tx == 0);
#pragma unroll
  for (int rr = 0; rr < 8; ++rr) {
    const int r = (rr < 4) ? (4 * ty + rr) : (32 + 4 * ty + (rr - 4));
    float bv = 3.0e38f; int bj = 0;
#pragma unroll
    for (int jj = 0; jj < 8; ++jj) {
      const float v = e2nj[jj] - 2.0f * acc[rr][jj];
      if (v < bv) { bv = v; bj = jc[jj]; }   // j ascending per thread -> first-min tiebreak
    }
#pragma unroll
    for (int mask = 1; mask <= 16; mask <<= 1) {  // reduce across tx lanes (ty bit untouched)
      const float ov = __shfl_xor(bv, mask);
      const int   oj = __shfl_xor(bj, mask);
      if (ov < bv || (ov == bv && oj < bj)) { bv = ov; bj = oj; }
    }
    if (writer) {
      idx_s[r] = bj;
      atomicAdd(&hist[bj], 1);
      // ||x - e_raw||^2 = ||x||^2 + ||e_raw||^2 - scale*(||e_n||^2 - d_min)
      commit_loc += x2a[rr] + e2r_s[bj] - (e2n_s[bj] - bv) * scl_s[bj];
    }
  }
  if (writer) atomicAdd(commit_sum, commit_loc);
  __syncthreads();

  // ---- gather: quantized row = raw embedding[argmin] ----
  const float4* emb4 = reinterpret_cast<const float4*>(emb);
  float4* out4 = reinterpret_cast<float4*>(out);
#pragma unroll 4
  for (int i = 0; i < kBM; ++i) {
    const int m = idx_s[i];
    out4[(size_t)(r0 + i) * (kD / 4) + t] = emb4[(size_t)m * (kD / 4) + t];
  }
}

// ---------------- kernel 3: scalars ----------------
__global__ __launch_bounds__(256) void vq_final(const int* __restrict__ hist,
                                                const float* __restrict__ commit_sum,
                                                float* __restrict__ out) {
  const int t = threadIdx.x;
  const float p = (float)hist[t] * (1.0f / (float)kNT);
  float s = p * logf(p + 1e-10f);
#pragma unroll
  for (int mask = 32; mask >= 1; mask >>= 1) s += __shfl_xor(s, mask);
  __shared__ float red[4];
  if ((t & 63) == 0) red[t >> 6] = s;
  __syncthreads();
  if (t == 0) {
    const float ent = red[0] + red[1] + red[2] + red[3];
    out[kQElems]     = commit_sum[0] * (1.0f / (float)kQElems);
    out[kQElems + 1] = expf(-ent);
  }
}

extern "C" void kernel_launch(void* const* d_in, const int* in_sizes, int n_in,
                              void* d_out, int out_size, void* d_ws, size_t ws_size,
                              hipStream_t stream) {
  (void)in_sizes; (void)n_in; (void)out_size; (void)ws_size;
  const float* x   = (const float*)d_in[0];
  const float* emb = (const float*)d_in[1];
  float* out = (float*)d_out;
  float* ws  = (float*)d_ws;

  hipMemsetAsync((char*)d_ws + (size_t)WS_COM * 4, 0, WS_ZERO_BYTES, stream);
  hipLaunchKernelGGL(vq_normalize, dim3(kM), dim3(256), 0, stream, emb, ws);
  hipLaunchKernelGGL(vq_main, dim3(kNT / kBM), dim3(256), 0, stream,
                     x, emb, ws, out, ws + WS_COM, (int*)(ws + WS_HIST));
  hipLaunchKernelGGL(vq_final, dim3(1), dim3(256), 0, stream,
                     (const int*)(ws + WS_HIST), ws + WS_COM, out);
}

// Round 3
// 247.820 us; speedup vs baseline: 1.7265x; 1.7265x over previous
//
#include <hip/hip_runtime.h>
#include <cstdint>
#include <cstddef>

// VQ-VAE quantization forward, MI355X/gfx950 — bf16 split-precision MFMA version.
// dot(x, e_norm) = xh*eh + xh*el + xl*eh  (3x mfma_f32_16x16x32_bf16, fp32 accum)

typedef __attribute__((ext_vector_type(8))) short short8;
typedef __attribute__((ext_vector_type(4))) float f32x4;

namespace {
constexpr int kNT = 25600;           // N*T rows
constexpr int kD  = 1024;            // feature dim
constexpr int kM  = 256;             // codebook size
constexpr size_t kQElems = (size_t)kNT * kD;

// ws layout (float units). Codebook images: 32 chunks x [n=256][k=32] bf16,
// 16B sub-blocks swizzled: element idx = c*8192 + n*32 + (g ^ ((n>>1)&3))*8 + (k&7)
constexpr int WS_IMG_H = 0;                    // 262144 ushort = 131072 floats
constexpr int WS_IMG_L = 131072;               // 262144 ushort
constexpr int WS_E2N   = 262144;               // ||e_norm||^2 (256)
constexpr int WS_SCL   = WS_E2N + kM;          // ||e_raw|| + 1e-4 (256)
constexpr int WS_E2R   = WS_SCL + kM;          // ||e_raw||^2 (256)
constexpr int WS_COM   = WS_E2R + kM;          // commitment accumulator
constexpr int WS_HIST  = WS_COM + 4;           // histogram 256 ints
constexpr int WS_ZERO_BYTES = (WS_HIST + kM - WS_COM) * 4;
}

typedef __attribute__((address_space(3))) unsigned int        lds_u32;
typedef const __attribute__((address_space(1))) unsigned int  glb_u32;

__device__ __forceinline__ void gl2lds16(const void* g, void* l) {
  __builtin_amdgcn_global_load_lds((glb_u32*)g, (lds_u32*)l, 16, 0, 0);
}

// ---------------- kernel 1: normalize codebook -> swizzled bf16 hi/lo images + stats ----
__global__ __launch_bounds__(256) void vq_normalize(const float* __restrict__ emb,
                                                    float* __restrict__ ws) {
  const int m = blockIdx.x;
  const int t = threadIdx.x;
  const float4 v = reinterpret_cast<const float4*>(emb + (size_t)m * kD)[t];
  float s = v.x * v.x + v.y * v.y + v.z * v.z + v.w * v.w;
#pragma unroll
  for (int mask = 32; mask >= 1; mask >>= 1) s += __shfl_xor(s, mask);
  __shared__ float red[4];
  if ((t & 63) == 0) red[t >> 6] = s;
  __syncthreads();
  const float tot = red[0] + red[1] + red[2] + red[3];
  const float sc  = sqrtf(tot) + 1e-4f;
  const float inv = 1.0f / sc;
  const float4 nv = make_float4(v.x * inv, v.y * inv, v.z * inv, v.w * inv);

  float s2 = nv.x * nv.x + nv.y * nv.y + nv.z * nv.z + nv.w * nv.w;
#pragma unroll
  for (int mask = 32; mask >= 1; mask >>= 1) s2 += __shfl_xor(s2, mask);
  __syncthreads();
  if ((t & 63) == 0) red[t >> 6] = s2;
  __syncthreads();
  if (t == 0) {
    ws[WS_E2N + m] = red[0] + red[1] + red[2] + red[3];
    ws[WS_SCL + m] = sc;
    ws[WS_E2R + m] = tot;
  }

  // hi/lo truncation split, packed to the swizzled image
  unsigned short* imgh = (unsigned short*)(ws + WS_IMG_H);
  unsigned short* imgl = (unsigned short*)(ws + WS_IMG_L);
  const int c  = t >> 3;              // k-chunk (k = 4t..4t+3)
  const int g  = (t >> 1) & 3;        // 8-elem group within chunk
  const int sq = g ^ ((m >> 1) & 3);  // bank swizzle
  const int base = c * 8192 + m * 32 + sq * 8 + 4 * (t & 1);
  ushort4 hq, lq;
#pragma unroll
  for (int j = 0; j < 4; ++j) {
    const float fv = (&nv.x)[j];
    const unsigned int b = __float_as_uint(fv);
    const unsigned short hi = (unsigned short)(b >> 16);
    const float lof = fv - __uint_as_float(b & 0xFFFF0000u);
    const unsigned short lo = (unsigned short)(__float_as_uint(lof) >> 16);
    (&hq.x)[j] = hi; (&lq.x)[j] = lo;
  }
  *(ushort4*)(imgh + base) = hq;
  *(ushort4*)(imgl + base) = lq;
}

// ---------------- kernel 2: MFMA distances + argmin + gather + stats ----------------
// 400 blocks x 256 threads (4 waves). Block: 64 rows x 256 codes, K split in halves.
// wave w: rows [32*(w&1), +32), K-half (w>>1), comp-staging slot w.
__global__ __launch_bounds__(256, 2) void vq_main(const float* __restrict__ x,
                                                  const float* __restrict__ emb,
                                                  const float* __restrict__ wsc,
                                                  float* __restrict__ out,
                                                  float* __restrict__ commit_sum,
                                                  int* __restrict__ hist) {
  __shared__ char pool[65536];     // staging: 4 slots x 16KB; aliased as Sd[64][256] f32 after loop
  __shared__ float e2n_s[kM], scl_s[kM], e2r_s[kM], x2s[64];
  __shared__ int idx_s[64];

  const int t  = threadIdx.x;
  const int l  = t & 63;
  const int w  = t >> 6;
  const int h  = w >> 1;     // K-half
  const int rw = w & 1;      // row-half
  const int r0 = blockIdx.x * 64;

  e2n_s[t] = wsc[WS_E2N + t];
  scl_s[t] = wsc[WS_SCL + t];
  e2r_s[t] = wsc[WS_E2R + t];

  const unsigned short* img = (const unsigned short*)(wsc + ((w & 1) ? WS_IMG_L : WS_IMG_H));
  char* myslot = pool + w * 16384;

  const int nlo = l & 15;
  const int sq  = (l >> 4) ^ ((l >> 1) & 3);
  const int rowA   = r0 + rw * 32 + nlo;          // + rt*16
  const int kbase0 = h * 512 + ((l >> 4) << 3);   // + cc*32

  f32x4 acc[2][16];
#pragma unroll
  for (int rt = 0; rt < 2; ++rt)
#pragma unroll
    for (int ct = 0; ct < 16; ++ct) acc[rt][ct] = (f32x4)0.0f;
  float x2[2] = {0.0f, 0.0f};

#pragma unroll 1
  for (int cc = 0; cc < 16; ++cc) {
    // stage this wave's 16KB image chunk (slot w): chunk c = h*16+cc of img[w&1]
    const unsigned short* src = img + (size_t)(h * 16 + cc) * 8192 + l * 8;
#pragma unroll
    for (int it = 0; it < 16; ++it)
      gl2lds16(src + it * 512, myslot + it * 1024);

    // A: read 8 fp32 of x per row-tile (registers; no LDS round-trip)
    float4 f[2][2];
#pragma unroll
    for (int rt = 0; rt < 2; ++rt) {
      const float* xp = x + (size_t)(rowA + rt * 16) * kD + (cc * 32 + kbase0);
      f[rt][0] = *(const float4*)xp;
      f[rt][1] = *(const float4*)(xp + 4);
    }
    __syncthreads();   // staging (and A loads) drained

    short8 ah[2], al[2];
#pragma unroll
    for (int rt = 0; rt < 2; ++rt) {
      union { short8 v; unsigned short u[8]; } H, L;
#pragma unroll
      for (int j = 0; j < 8; ++j) {
        const float fv = (&f[rt][j >> 2].x)[j & 3];
        const unsigned int b = __float_as_uint(fv);
        H.u[j] = (unsigned short)(b >> 16);
        const float lof = fv - __uint_as_float(b & 0xFFFF0000u);
        L.u[j] = (unsigned short)(__float_as_uint(lof) >> 16);
        x2[rt] += fv * fv;
      }
      ah[rt] = H.v; al[rt] = L.v;
    }

    const char* bh_base = pool + (h * 2 + 0) * 16384;
    const char* bl_base = pool + (h * 2 + 1) * 16384;
#pragma unroll
    for (int ct = 0; ct < 16; ++ct) {
      const int off = (ct * 16 + nlo) * 64 + sq * 16;
      const short8 bh = *(const short8*)(bh_base + off);
      const short8 bl = *(const short8*)(bl_base + off);
#pragma unroll
      for (int rt = 0; rt < 2; ++rt) {
        acc[rt][ct] = __builtin_amdgcn_mfma_f32_16x16x32_bf16(ah[rt], bh, acc[rt][ct], 0, 0, 0);
        acc[rt][ct] = __builtin_amdgcn_mfma_f32_16x16x32_bf16(ah[rt], bl, acc[rt][ct], 0, 0, 0);
        acc[rt][ct] = __builtin_amdgcn_mfma_f32_16x16x32_bf16(al[rt], bh, acc[rt][ct], 0, 0, 0);
      }
    }
    __syncthreads();   // LDS reuse next iteration
  }

  // x2: sum across the 4 k-quads (lanes sharing l&15)
#pragma unroll
  for (int rt = 0; rt < 2; ++rt) {
    x2[rt] += __shfl_xor(x2[rt], 16);
    x2[rt] += __shfl_xor(x2[rt], 32);
  }

  // combine K-half partials in LDS (Sd aliases staging pool)
  float* Sd = (float*)pool;
  if (h == 0) {
#pragma unroll
    for (int rt = 0; rt < 2; ++rt) {
#pragma unroll
      for (int ct = 0; ct < 16; ++ct)
#pragma unroll
        for (int rg = 0; rg < 4; ++rg) {
          const int row = rw * 32 + rt * 16 + (l >> 4) * 4 + rg;
          Sd[row * 256 + ct * 16 + nlo] = -2.0f * acc[rt][ct][rg];
        }
      if (l < 16) x2s[rw * 32 + rt * 16 + l] = x2[rt];
    }
  }
  __syncthreads();
  if (h == 1) {
#pragma unroll
    for (int rt = 0; rt < 2; ++rt) {
#pragma unroll
      for (int ct = 0; ct < 16; ++ct)
#pragma unroll
        for (int rg = 0; rg < 4; ++rg) {
          const int row = rw * 32 + rt * 16 + (l >> 4) * 4 + rg;
          Sd[row * 256 + ct * 16 + nlo] -= 2.0f * acc[rt][ct][rg];
        }
      if (l < 16) x2s[rw * 32 + rt * 16 + l] += x2[rt];
    }
  }
  __syncthreads();

  // argmin: thread t -> row t>>2, col quarter (t&3)*64. v = e2n[j] - 2*dot.
  {
    const int row = t >> 2, q = t & 3;
    float bv = 3.0e38f; int bj = 0;
    const float* Sr = Sd + row * 256 + q * 64;
    const float* En = e2n_s + q * 64;
    for (int jj = 0; jj < 64; ++jj) {
      const int jloc = (jj + 2 * row) & 63;        // bank-spread scan
      const float v = En[jloc] + Sr[jloc];
      const int j = q * 64 + jloc;
      if (v < bv || (v == bv && j < bj)) { bv = v; bj = j; }
    }
#pragma unroll
    for (int m = 1; m <= 2; m <<= 1) {
      const float ov = __shfl_xor(bv, m);
      const int   oj = __shfl_xor(bj, m);
      if (ov < bv || (ov == bv && oj < bj)) { bv = ov; bj = oj; }
    }
    if (q == 0) {
      idx_s[row] = bj;
      atomicAdd(&hist[bj], 1);
      // ||x - e_raw||^2 = ||x||^2 + ||e_raw||^2 - (e2n - bv)*scl   [(e2n-bv) = 2*dot]
      const float cl = x2s[row] + e2r_s[bj] - (e2n_s[bj] - bv) * scl_s[bj];
      atomicAdd(commit_sum, cl);
    }
  }
  __syncthreads();

  // gather: quantized row = raw embedding[argmin]
  const float4* emb4 = reinterpret_cast<const float4*>(emb);
  float4* out4 = reinterpret_cast<float4*>(out);
#pragma unroll 4
  for (int i = 0; i < 64; ++i) {
    const int m = idx_s[i];
    out4[(size_t)(r0 + i) * (kD / 4) + t] = emb4[(size_t)m * (kD / 4) + t];
  }
}

// ---------------- kernel 3: scalars ----------------
__global__ __launch_bounds__(256) void vq_final(const int* __restrict__ hist,
                                                const float* __restrict__ commit_sum,
                                                float* __restrict__ out) {
  const int t = threadIdx.x;
  const float p = (float)hist[t] * (1.0f / (float)kNT);
  float s = p * logf(p + 1e-10f);
#pragma unroll
  for (int mask = 32; mask >= 1; mask >>= 1) s += __shfl_xor(s, mask);
  __shared__ float red[4];
  if ((t & 63) == 0) red[t >> 6] = s;
  __syncthreads();
  if (t == 0) {
    const float ent = red[0] + red[1] + red[2] + red[3];
    out[kQElems]     = commit_sum[0] * (1.0f / (float)kQElems);
    out[kQElems + 1] = expf(-ent);
  }
}

extern "C" void kernel_launch(void* const* d_in, const int* in_sizes, int n_in,
                              void* d_out, int out_size, void* d_ws, size_t ws_size,
                              hipStream_t stream) {
  (void)in_sizes; (void)n_in; (void)out_size; (void)ws_size;
  const float* x   = (const float*)d_in[0];
  const float* emb = (const float*)d_in[1];
  float* out = (float*)d_out;
  float* ws  = (float*)d_ws;

  hipMemsetAsync((char*)d_ws + (size_t)WS_COM * 4, 0, WS_ZERO_BYTES, stream);
  hipLaunchKernelGGL(vq_normalize, dim3(kM), dim3(256), 0, stream, emb, ws);
  hipLaunchKernelGGL(vq_main, dim3(kNT / 64), dim3(256), 0, stream,
                     x, emb, ws, out, ws + WS_COM, (int*)(ws + WS_HIST));
  hipLaunchKernelGGL(vq_final, dim3(1), dim3(256), 0, stream,
                     (const int*)(ws + WS_HIST), ws + WS_COM, out);
}